// Round 1
// baseline (4715.161 us; speedup 1.0000x reference)
//
#include <hip/hip_runtime.h>
#include <math.h>

#define NVOX 120000
#define CDIM 128
#define NWIN 5000
#define TWIN 36
#define FILLN 24
#define HWPIX 102400
#define WIMG 320

// ============================================================================
// GEMM family: tile 64 rows x 128 cols, 256 threads.
// thread (bi,bj): bi=t/16, bj=t%16; computes rows bi+16*rr (rr<4), cols bj+16*cc (cc<8).
// LDS: As[64][68], Ws[128][68]  (pitch 68: bank = 4*row+k -> <=2-way conflicts, free)
// K staged in chunks of 64.
// ============================================================================

__global__ __launch_bounds__(256) void qkv_kernel(
    const float* __restrict__ x, const float* __restrict__ pos,
    const int* __restrict__ ind, const float* __restrict__ ipw,
    const float* __restrict__ ipb, float* __restrict__ qb,
    float* __restrict__ kb, float* __restrict__ vb)
{
  __shared__ float lds[13056];
  float* As = lds;          // [64][68]
  float* Ws = lds + 4352;   // [128][68]
  const int t = threadIdx.x;
  const int bi = t >> 4, bj = t & 15;
  const int mbase = blockIdx.x * 64;
  const int sec = blockIdx.y;   // 0=q, 1=k, 2=v
  float acc[4][8];
#pragma unroll
  for (int r = 0; r < 4; ++r)
#pragma unroll
    for (int c = 0; c < 8; ++c) acc[r][c] = 0.f;

  for (int kc = 0; kc < 2; ++kc) {
#pragma unroll
    for (int u = 0; u < 4; ++u) {
      int fi = t + 256 * u;
      int row = fi >> 4, c4 = fi & 15;
      int vox = mbase + row;
      float4 av = ((const float4*)x)[(size_t)vox * 32 + kc * 16 + c4];
      if (sec < 2) {
        int s = ind[vox];  // s = w*36 + t, pos row == s
        float4 pv = ((const float4*)pos)[(size_t)s * 32 + kc * 16 + c4];
        av.x += pv.x; av.y += pv.y; av.z += pv.z; av.w += pv.w;
      }
      *(float4*)&As[row * 68 + c4 * 4] = av;
    }
#pragma unroll
    for (int u = 0; u < 8; ++u) {
      int fi = t + 256 * u;
      int row = fi >> 4, c4 = fi & 15;
      float4 wv = ((const float4*)ipw)[(size_t)(sec * 128 + row) * 32 + kc * 16 + c4];
      *(float4*)&Ws[row * 68 + c4 * 4] = wv;
    }
    __syncthreads();
#pragma unroll 4
    for (int kk = 0; kk < 64; ++kk) {
      float a[4], wv[8];
#pragma unroll
      for (int r = 0; r < 4; ++r) a[r] = As[(bi + 16 * r) * 68 + kk];
#pragma unroll
      for (int c = 0; c < 8; ++c) wv[c] = Ws[(bj + 16 * c) * 68 + kk];
#pragma unroll
      for (int r = 0; r < 4; ++r)
#pragma unroll
        for (int c = 0; c < 8; ++c) acc[r][c] = fmaf(a[r], wv[c], acc[r][c]);
    }
    __syncthreads();
  }
  // epilogue: stage, then scatter to slot-major with bias
  float* Ys = lds;  // [64][132]
#pragma unroll
  for (int r = 0; r < 4; ++r)
#pragma unroll
    for (int c = 0; c < 8; ++c) Ys[(bi + 16 * r) * 132 + bj + 16 * c] = acc[r][c];
  __syncthreads();
  float* dst = (sec == 0) ? qb : ((sec == 1) ? kb : vb);
  for (int idx = t; idx < 8192; idx += 256) {
    int row = idx >> 7, col = idx & 127;
    int s = ind[mbase + row];
    int slot = (s / 36) * 24 + (s % 36);
    dst[(size_t)slot * 128 + col] = Ys[row * 132 + col] + ipb[sec * 128 + col];
  }
}

__global__ __launch_bounds__(256) void outln_kernel(
    const float* __restrict__ o, const int* __restrict__ ind,
    const float* __restrict__ opw, const float* __restrict__ opb,
    const float* __restrict__ xres, const float* __restrict__ lnw,
    const float* __restrict__ lnb, float* __restrict__ hout)
{
  __shared__ float lds[13056];
  float* As = lds;
  float* Ws = lds + 4352;
  const int t = threadIdx.x;
  const int bi = t >> 4, bj = t & 15;
  const int mbase = blockIdx.x * 64;
  float acc[4][8];
#pragma unroll
  for (int r = 0; r < 4; ++r)
#pragma unroll
    for (int c = 0; c < 8; ++c) acc[r][c] = 0.f;

  for (int kc = 0; kc < 2; ++kc) {
#pragma unroll
    for (int u = 0; u < 4; ++u) {
      int fi = t + 256 * u;
      int row = fi >> 4, c4 = fi & 15;
      int vox = mbase + row;
      int s = ind[vox];
      int slot = (s / 36) * 24 + (s % 36);
      float4 av = ((const float4*)o)[(size_t)slot * 32 + kc * 16 + c4];
      *(float4*)&As[row * 68 + c4 * 4] = av;
    }
#pragma unroll
    for (int u = 0; u < 8; ++u) {
      int fi = t + 256 * u;
      int row = fi >> 4, c4 = fi & 15;
      float4 wv = ((const float4*)opw)[(size_t)row * 32 + kc * 16 + c4];
      *(float4*)&Ws[row * 68 + c4 * 4] = wv;
    }
    __syncthreads();
#pragma unroll 4
    for (int kk = 0; kk < 64; ++kk) {
      float a[4], wv[8];
#pragma unroll
      for (int r = 0; r < 4; ++r) a[r] = As[(bi + 16 * r) * 68 + kk];
#pragma unroll
      for (int c = 0; c < 8; ++c) wv[c] = Ws[(bj + 16 * c) * 68 + kk];
#pragma unroll
      for (int r = 0; r < 4; ++r)
#pragma unroll
        for (int c = 0; c < 8; ++c) acc[r][c] = fmaf(a[r], wv[c], acc[r][c]);
    }
    __syncthreads();
  }
  float* Ys = lds;            // [64][132]
  float* p1 = lds + 8448;     // [4][64]
  float* p2 = lds + 8704;
  float* Ms = lds + 8960;
  float* Rs = lds + 9024;
#pragma unroll
  for (int r = 0; r < 4; ++r)
#pragma unroll
    for (int c = 0; c < 8; ++c)
      Ys[(bi + 16 * r) * 132 + bj + 16 * c] = acc[r][c] + opb[bj + 16 * c];
  __syncthreads();
  for (int idx = t; idx < 8192; idx += 256) {
    int row = idx >> 7, col = idx & 127;
    Ys[row * 132 + col] += xres[(size_t)(mbase + row) * 128 + col];
  }
  __syncthreads();
  {
    int r = t & 63, g = t >> 6;
    float s = 0.f, s2 = 0.f;
    for (int c = g * 32; c < g * 32 + 32; ++c) { float v = Ys[r * 132 + c]; s += v; s2 += v * v; }
    p1[g * 64 + r] = s; p2[g * 64 + r] = s2;
  }
  __syncthreads();
  if (t < 64) {
    float s = p1[t] + p1[64 + t] + p1[128 + t] + p1[192 + t];
    float s2 = p2[t] + p2[64 + t] + p2[128 + t] + p2[192 + t];
    float m = s * (1.f / 128.f);
    float var = s2 * (1.f / 128.f) - m * m;
    Ms[t] = m; Rs[t] = rsqrtf(var + 1e-5f);
  }
  __syncthreads();
  for (int idx = t; idx < 8192; idx += 256) {
    int row = idx >> 7, col = idx & 127;
    hout[(size_t)(mbase + row) * 128 + col] =
        (Ys[row * 132 + col] - Ms[row]) * Rs[row] * lnw[col] + lnb[col];
  }
}

__global__ __launch_bounds__(256) void ffn1_kernel(
    const float* __restrict__ h, const float* __restrict__ w1,
    const float* __restrict__ b1, float* __restrict__ ff)
{
  __shared__ float lds[13056];
  float* As = lds;
  float* Ws = lds + 4352;
  const int t = threadIdx.x;
  const int bi = t >> 4, bj = t & 15;
  const int mbase = blockIdx.x * 64;
  const int by = blockIdx.y;   // col block (0..1) of 256
  float acc[4][8];
#pragma unroll
  for (int r = 0; r < 4; ++r)
#pragma unroll
    for (int c = 0; c < 8; ++c) acc[r][c] = 0.f;

  for (int kc = 0; kc < 2; ++kc) {
#pragma unroll
    for (int u = 0; u < 4; ++u) {
      int fi = t + 256 * u;
      int row = fi >> 4, c4 = fi & 15;
      float4 av = ((const float4*)h)[(size_t)(mbase + row) * 32 + kc * 16 + c4];
      *(float4*)&As[row * 68 + c4 * 4] = av;
    }
#pragma unroll
    for (int u = 0; u < 8; ++u) {
      int fi = t + 256 * u;
      int row = fi >> 4, c4 = fi & 15;
      float4 wv = ((const float4*)w1)[(size_t)(by * 128 + row) * 32 + kc * 16 + c4];
      *(float4*)&Ws[row * 68 + c4 * 4] = wv;
    }
    __syncthreads();
#pragma unroll 4
    for (int kk = 0; kk < 64; ++kk) {
      float a[4], wv[8];
#pragma unroll
      for (int r = 0; r < 4; ++r) a[r] = As[(bi + 16 * r) * 68 + kk];
#pragma unroll
      for (int c = 0; c < 8; ++c) wv[c] = Ws[(bj + 16 * c) * 68 + kk];
#pragma unroll
      for (int r = 0; r < 4; ++r)
#pragma unroll
        for (int c = 0; c < 8; ++c) acc[r][c] = fmaf(a[r], wv[c], acc[r][c]);
    }
    __syncthreads();
  }
  float* Ys = lds;
#pragma unroll
  for (int r = 0; r < 4; ++r)
#pragma unroll
    for (int c = 0; c < 8; ++c) Ys[(bi + 16 * r) * 132 + bj + 16 * c] = acc[r][c];
  __syncthreads();
  for (int idx = t; idx < 8192; idx += 256) {
    int row = idx >> 7, col = idx & 127;
    int colg = by * 128 + col;
    float v = Ys[row * 132 + col] + b1[colg];
    float g = 0.5f * v * (1.f + erff(v * 0.70710678f));
    ff[(size_t)(mbase + row) * 256 + colg] = g;
  }
}

__global__ __launch_bounds__(256) void ffn2_kernel(
    const float* __restrict__ ff, const float* __restrict__ w2,
    const float* __restrict__ b2, const float* __restrict__ hres,
    const float* __restrict__ lnw, const float* __restrict__ lnb,
    float* __restrict__ xout)
{
  __shared__ float lds[13056];
  float* As = lds;
  float* Ws = lds + 4352;
  const int t = threadIdx.x;
  const int bi = t >> 4, bj = t & 15;
  const int mbase = blockIdx.x * 64;
  float acc[4][8];
#pragma unroll
  for (int r = 0; r < 4; ++r)
#pragma unroll
    for (int c = 0; c < 8; ++c) acc[r][c] = 0.f;

  for (int kc = 0; kc < 4; ++kc) {   // K = 256
#pragma unroll
    for (int u = 0; u < 4; ++u) {
      int fi = t + 256 * u;
      int row = fi >> 4, c4 = fi & 15;
      float4 av = ((const float4*)ff)[(size_t)(mbase + row) * 64 + kc * 16 + c4];
      *(float4*)&As[row * 68 + c4 * 4] = av;
    }
#pragma unroll
    for (int u = 0; u < 8; ++u) {
      int fi = t + 256 * u;
      int row = fi >> 4, c4 = fi & 15;
      float4 wv = ((const float4*)w2)[(size_t)row * 64 + kc * 16 + c4];
      *(float4*)&Ws[row * 68 + c4 * 4] = wv;
    }
    __syncthreads();
#pragma unroll 4
    for (int kk = 0; kk < 64; ++kk) {
      float a[4], wv[8];
#pragma unroll
      for (int r = 0; r < 4; ++r) a[r] = As[(bi + 16 * r) * 68 + kk];
#pragma unroll
      for (int c = 0; c < 8; ++c) wv[c] = Ws[(bj + 16 * c) * 68 + kk];
#pragma unroll
      for (int r = 0; r < 4; ++r)
#pragma unroll
        for (int c = 0; c < 8; ++c) acc[r][c] = fmaf(a[r], wv[c], acc[r][c]);
    }
    __syncthreads();
  }
  float* Ys = lds;
  float* p1 = lds + 8448;
  float* p2 = lds + 8704;
  float* Ms = lds + 8960;
  float* Rs = lds + 9024;
#pragma unroll
  for (int r = 0; r < 4; ++r)
#pragma unroll
    for (int c = 0; c < 8; ++c)
      Ys[(bi + 16 * r) * 132 + bj + 16 * c] = acc[r][c] + b2[bj + 16 * c];
  __syncthreads();
  for (int idx = t; idx < 8192; idx += 256) {
    int row = idx >> 7, col = idx & 127;
    Ys[row * 132 + col] += hres[(size_t)(mbase + row) * 128 + col];
  }
  __syncthreads();
  {
    int r = t & 63, g = t >> 6;
    float s = 0.f, s2 = 0.f;
    for (int c = g * 32; c < g * 32 + 32; ++c) { float v = Ys[r * 132 + c]; s += v; s2 += v * v; }
    p1[g * 64 + r] = s; p2[g * 64 + r] = s2;
  }
  __syncthreads();
  if (t < 64) {
    float s = p1[t] + p1[64 + t] + p1[128 + t] + p1[192 + t];
    float s2 = p2[t] + p2[64 + t] + p2[128 + t] + p2[192 + t];
    float m = s * (1.f / 128.f);
    float var = s2 * (1.f / 128.f) - m * m;
    Ms[t] = m; Rs[t] = rsqrtf(var + 1e-5f);
  }
  __syncthreads();
  for (int idx = t; idx < 8192; idx += 256) {
    int row = idx >> 7, col = idx & 127;
    xout[(size_t)(mbase + row) * 128 + col] =
        (Ys[row * 132 + col] - Ms[row]) * Rs[row] * lnw[col] + lnb[col];
  }
}

// ============================================================================
// Attention: one block per window. 24 real tokens only (masked slots dead).
// Writes O back into the Q buffer (block-local rows, read fully before write).
// ============================================================================
__global__ __launch_bounds__(256) void attn_kernel(
    float* __restrict__ qb, const float* __restrict__ kb, const float* __restrict__ vb)
{
  __shared__ float lds[14112];
  float* Qs = lds;           // [24][132]
  float* Ks = lds + 3168;
  float* Vs = lds + 6336;
  float* S  = lds + 9504;    // [8][24][24]
  const int t = threadIdx.x;
  const size_t base = (size_t)blockIdx.x * 24 * 128;
  for (int fi = t; fi < 2304; fi += 256) {
    int arr = fi / 768, rem = fi % 768;
    int row = rem >> 5, c4 = rem & 31;
    const float* src = arr == 0 ? qb : (arr == 1 ? kb : vb);
    float4 v = ((const float4*)(src + base))[row * 32 + c4];
    float* dstl = lds + arr * 3168;
    *(float4*)&dstl[row * 132 + c4 * 4] = v;
  }
  __syncthreads();
  for (int idx = t; idx < 4608; idx += 256) {
    int hh = idx / 576, rem = idx % 576;
    int qq = rem / 24, kk = rem % 24;
    const float* qp = &Qs[qq * 132 + hh * 16];
    const float* kp = &Ks[kk * 132 + hh * 16];
    float s = 0.f;
#pragma unroll
    for (int d = 0; d < 16; ++d) s = fmaf(qp[d], kp[d], s);
    S[idx] = s * 0.25f;   // SCALE = HD^-0.5
  }
  __syncthreads();
  if (t < 192) {
    float* rowp = &S[t * 24];
    float m = rowp[0];
#pragma unroll
    for (int k2 = 1; k2 < 24; ++k2) m = fmaxf(m, rowp[k2]);
    float sum = 0.f;
#pragma unroll
    for (int k2 = 0; k2 < 24; ++k2) { float e = __expf(rowp[k2] - m); rowp[k2] = e; sum += e; }
    float inv = 1.f / sum;
#pragma unroll
    for (int k2 = 0; k2 < 24; ++k2) rowp[k2] *= inv;
  }
  __syncthreads();
  for (int idx = t; idx < 3072; idx += 256) {
    int hh = idx / 384, rem = idx % 384;
    int qq = rem >> 4, dd = rem & 15;
    const float* pp = &S[hh * 576 + qq * 24];
    const float* vp = &Vs[hh * 16 + dd];
    float o = 0.f;
#pragma unroll
    for (int k2 = 0; k2 < 24; ++k2) o = fmaf(pp[k2], vp[k2 * 132], o);
    qb[base + qq * 128 + hh * 16 + dd] = o;
  }
}

// ============================================================================
// Scatter to canvas (last-voxel-wins via atomicMax on index map) + convs
// ============================================================================
__global__ void idx_init_kernel(int* __restrict__ idxmap) {
  int i = blockIdx.x * 256 + threadIdx.x;
  if (i < 2 * HWPIX) idxmap[i] = -1;
}

__global__ void scatter_kernel(const int* __restrict__ coors, int* __restrict__ idxmap) {
  int i = blockIdx.x * 256 + threadIdx.x;
  if (i >= NVOX) return;
  int b = coors[i * 4 + 0], y = coors[i * 4 + 2], xx = coors[i * 4 + 3];
  atomicMax(&idxmap[b * HWPIX + y * WIMG + xx], i);
}

__global__ void canvas_kernel(const float* __restrict__ x, const int* __restrict__ idxmap,
                              float* __restrict__ canvas) {
  int idx = blockIdx.x * 256 + threadIdx.x;   // over 204800*32 float4s
  if (idx >= 2 * HWPIX * 32) return;
  int cell = idx >> 5, c4 = idx & 31;
  int vox = idxmap[cell];
  float4 v = make_float4(0.f, 0.f, 0.f, 0.f);
  if (vox >= 0) v = ((const float4*)x)[(size_t)vox * 32 + c4];
  ((float4*)canvas)[idx] = v;
}

__global__ void transpose_w_kernel(const float* __restrict__ w, float* __restrict__ wT) {
  int idx = blockIdx.x * 256 + threadIdx.x;
  if (idx >= 2 * 9 * 128 * 128) return;
  int ci = idx & 127;
  int co = (idx >> 7) & 127;
  int tap = (idx >> 14) % 9;
  int conv = idx / (9 * 16384);
  wT[idx] = w[((size_t)(conv * 128 + co) * 128 + ci) * 9 + tap];
}

// Direct conv 3x3 pad 1, NHWC in. Block: 64 px (one row) x 128 cout.
template <int NCHW_OUT>
__global__ __launch_bounds__(256) void conv_kernel(
    const float* __restrict__ in, const float* __restrict__ wT, float* __restrict__ out)
{
  __shared__ float lds[10752];   // patch [32][3][68] = 6528, Wt [128][33] = 4224
  float* patch = lds;
  float* Wt = lds + 6528;
  const int t = threadIdx.x;
  const int bi = t >> 4, bj = t & 15;
  const int x0 = blockIdx.x * 64;
  const int y = blockIdx.y;
  const int b = blockIdx.z;
  const float* inb = in + (size_t)b * HWPIX * 128;
  float acc[4][8];
#pragma unroll
  for (int r = 0; r < 4; ++r)
#pragma unroll
    for (int c = 0; c < 8; ++c) acc[r][c] = 0.f;

  for (int cic = 0; cic < 4; ++cic) {
    __syncthreads();
    // load patch: 3 rows x 66 cols x 32 ci
    for (int fi = t; fi < 1584; fi += 256) {
      int pix = fi >> 3, c4 = fi & 7;
      int row = pix / 66, col = pix % 66;
      int gy = y + row - 1, gx = x0 + col - 1;
      float4 v = make_float4(0.f, 0.f, 0.f, 0.f);
      if (gy >= 0 && gy < 320 && gx >= 0 && gx < 320)
        v = ((const float4*)inb)[(size_t)(gy * 320 + gx) * 32 + cic * 8 + c4];
      int cb = c4 * 4;
      patch[(cb + 0) * 204 + row * 68 + col] = v.x;
      patch[(cb + 1) * 204 + row * 68 + col] = v.y;
      patch[(cb + 2) * 204 + row * 68 + col] = v.z;
      patch[(cb + 3) * 204 + row * 68 + col] = v.w;
    }
    for (int tap = 0; tap < 9; ++tap) {
      __syncthreads();
      for (int fi = t; fi < 1024; fi += 256) {
        int co = fi >> 3, c4 = fi & 7;
        float4 wv = ((const float4*)wT)[(size_t)(tap * 128 + co) * 32 + cic * 8 + c4];
        int cb = c4 * 4;
        Wt[co * 33 + cb + 0] = wv.x;
        Wt[co * 33 + cb + 1] = wv.y;
        Wt[co * 33 + cb + 2] = wv.z;
        Wt[co * 33 + cb + 3] = wv.w;
      }
      __syncthreads();
      int dy = tap / 3, dx = tap % 3;
#pragma unroll 4
      for (int ci = 0; ci < 32; ++ci) {
        float a[4], wv[8];
#pragma unroll
        for (int r = 0; r < 4; ++r) a[r] = patch[ci * 204 + dy * 68 + (bi + 16 * r) + dx];
#pragma unroll
        for (int c = 0; c < 8; ++c) wv[c] = Wt[(bj + 16 * c) * 33 + ci];
#pragma unroll
        for (int r = 0; r < 4; ++r)
#pragma unroll
          for (int c = 0; c < 8; ++c) acc[r][c] = fmaf(a[r], wv[c], acc[r][c]);
      }
    }
  }
  __syncthreads();
  float* Ys = lds;  // 8192 floats
#pragma unroll
  for (int r = 0; r < 4; ++r)
#pragma unroll
    for (int c = 0; c < 8; ++c) Ys[(bi + 16 * r) * 128 + bj + 16 * c] = acc[r][c];
  __syncthreads();
  if (NCHW_OUT) {
    for (int idx = t; idx < 8192; idx += 256) {
      int co = idx >> 6, px = idx & 63;
      float v = Ys[px * 128 + co];
      out[(size_t)(b * 128 + co) * HWPIX + y * 320 + x0 + px] = fmaxf(v, 0.f);
    }
  } else {
    for (int idx = t; idx < 8192; idx += 256) {
      int px = idx >> 7, co = idx & 127;
      out[(size_t)(b * HWPIX + y * 320 + x0 + px) * 128 + co] = fmaxf(Ys[idx], 0.f);
    }
  }
}

// ============================================================================
extern "C" void kernel_launch(void* const* d_in, const int* in_sizes, int n_in,
                              void* d_out, int out_size, void* d_ws, size_t ws_size,
                              hipStream_t stream)
{
  const float* voxel_feats = (const float*)d_in[0];
  const float* pos0 = (const float*)d_in[1];
  const float* pos1 = (const float*)d_in[2];
  const float* ipw = (const float*)d_in[3];
  const float* ipb = (const float*)d_in[4];
  const float* opw = (const float*)d_in[5];
  const float* opb = (const float*)d_in[6];
  const float* l1w = (const float*)d_in[7];
  const float* l1b = (const float*)d_in[8];
  const float* l2w = (const float*)d_in[9];
  const float* l2b = (const float*)d_in[10];
  const float* n1w = (const float*)d_in[11];
  const float* n1b = (const float*)d_in[12];
  const float* n2w = (const float*)d_in[13];
  const float* n2b = (const float*)d_in[14];
  const float* convw = (const float*)d_in[15];
  const int* coors = (const int*)d_in[16];
  const int* ind0 = (const int*)d_in[17];
  const int* ind1 = (const int*)d_in[18];
  // masks (d_in[19], d_in[20]) are deterministic (t >= FILL): unused.

  float* ws = (float*)d_ws;
  const size_t NC = (size_t)NVOX * CDIM;   // 15,360,000 floats
  float* bx = ws;            // x (current features)
  float* bq = ws + NC;       // Q slot-major; O after attn; also ff low half
  float* bk = ws + 2 * NC;   // K slot-major; ff high half; canvas low
  float* bv = ws + 3 * NC;   // V slot-major; canvas high
  float* bh = ws + 4 * NC;   // h (post-LN1); idxmap after layers
  float* wT = ws + 5 * NC;   // transposed conv weights (294912 floats)
  int* idxmap = (int*)bh;
  float* canvas = bk;        // NHWC, 26.21M floats <= 2*NC
  float* c1out = bx;         // NHWC, conv1 output
  float* ff = bq;            // 120000*256 = 30.72M floats == 2*NC exactly

  hipMemcpyAsync(bx, voxel_feats, NC * sizeof(float), hipMemcpyDeviceToDevice, stream);
  transpose_w_kernel<<<1152, 256, 0, stream>>>(convw, wT);

  for (int l = 0; l < 4; ++l) {
    const int* ind = (l & 1) ? ind1 : ind0;
    const float* pos = (l & 1) ? pos1 : pos0;
    qkv_kernel<<<dim3(1875, 3), 256, 0, stream>>>(
        bx, pos, ind, ipw + (size_t)l * 384 * 128, ipb + l * 384, bq, bk, bv);
    attn_kernel<<<NWIN, 256, 0, stream>>>(bq, bk, bv);  // O -> bq
    outln_kernel<<<1875, 256, 0, stream>>>(
        bq, ind, opw + (size_t)l * 128 * 128, opb + l * 128, bx,
        n1w + l * 128, n1b + l * 128, bh);
    ffn1_kernel<<<dim3(1875, 2), 256, 0, stream>>>(
        bh, l1w + (size_t)l * 256 * 128, l1b + l * 256, ff);
    ffn2_kernel<<<1875, 256, 0, stream>>>(
        ff, l2w + (size_t)l * 128 * 256, l2b + l * 128, bh,
        n2w + l * 128, n2b + l * 128, bx);
  }

  idx_init_kernel<<<800, 256, 0, stream>>>(idxmap);
  scatter_kernel<<<(NVOX + 255) / 256, 256, 0, stream>>>(coors, idxmap);
  canvas_kernel<<<25600, 256, 0, stream>>>(bx, idxmap, canvas);

  conv_kernel<0><<<dim3(5, 320, 2), 256, 0, stream>>>(canvas, wT, c1out);
  conv_kernel<1><<<dim3(5, 320, 2), 256, 0, stream>>>(c1out, wT + 9 * 128 * 128, (float*)d_out);
}

// Round 2
// 1610.275 us; speedup vs baseline: 2.9282x; 2.9282x over previous
//
#include <hip/hip_runtime.h>
#include <math.h>

#define NVOX 120000
#define CDIM 128
#define NWIN 5000
#define HWPIX 102400

typedef __attribute__((ext_vector_type(8))) short short8;
typedef __attribute__((ext_vector_type(4))) float f32x4;

__device__ __forceinline__ unsigned short f2bf(float f) {
  unsigned u = __float_as_uint(f);
  return (unsigned short)((u + 0x7FFFu + ((u >> 16) & 1u)) >> 16);
}
__device__ __forceinline__ unsigned pack2(float a, float b) {
  return (unsigned)f2bf(a) | ((unsigned)f2bf(b) << 16);
}
__device__ __forceinline__ void unpack2(unsigned u, float& a, float& b) {
  a = __uint_as_float(u << 16);
  b = __uint_as_float(u & 0xFFFF0000u);
}

// ============================================================================
// MFMA core: block = 256 thr = 4 waves. Block tile M=64 x N=128, K staged 128.
// Wave wv: rows 32*(wv>>1)+{0..31} (2 m-tiles), cols 64*(wv&1)+{0..63} (4 n-tiles).
// LDS pitch 136 bf16 (272 B -> bank stride 4 mod 32 -> 2-way, free).
// A-frag: A[m=lane&15][k=quad*8+j]; B-frag: W[n=lane&15][k=quad*8+j] (W is [N][K]).
// C/D: col=lane&15, row=quad*4+reg.
// ============================================================================
__device__ __forceinline__ void mma128(const short* __restrict__ As,
                                       const short* __restrict__ Ws,
                                       int aoff, int boff, f32x4 acc[2][4]) {
#pragma unroll
  for (int kc = 0; kc < 4; ++kc) {
    short8 a0 = *(const short8*)(As + aoff + kc * 32);
    short8 a1 = *(const short8*)(As + aoff + 136 * 16 + kc * 32);
#pragma unroll
    for (int nt = 0; nt < 4; ++nt) {
      short8 b = *(const short8*)(Ws + boff + nt * 136 * 16 + kc * 32);
      acc[0][nt] = __builtin_amdgcn_mfma_f32_16x16x32_bf16(a0, b, acc[0][nt], 0, 0, 0);
      acc[1][nt] = __builtin_amdgcn_mfma_f32_16x16x32_bf16(a1, b, acc[1][nt], 0, 0, 0);
    }
  }
}

// ---------------------------------------------------------------------------
__global__ __launch_bounds__(256) void cvt_kernel(const float* __restrict__ src,
                                                  unsigned short* __restrict__ dst, int n4) {
  int i = blockIdx.x * 256 + threadIdx.x;
  if (i >= n4) return;
  float4 v = ((const float4*)src)[i];
  uint2 o; o.x = pack2(v.x, v.y); o.y = pack2(v.z, v.w);
  ((uint2*)dst)[i] = o;
}

__global__ __launch_bounds__(256) void cvtT_kernel(const float* __restrict__ w,
                                                   unsigned short* __restrict__ wT) {
  int idx = blockIdx.x * 256 + threadIdx.x;
  if (idx >= 2 * 9 * 128 * 128) return;
  int ci = idx & 127;
  int co = (idx >> 7) & 127;
  int tap = (idx >> 14) % 9;
  int conv = idx / (9 * 16384);
  wT[idx] = f2bf(w[((size_t)(conv * 128 + co) * 128 + ci) * 9 + tap]);
}

// ---------------------------------------------------------------------------
__global__ __launch_bounds__(256) void qkv_kernel(
    const unsigned short* __restrict__ x, const float* __restrict__ pos,
    const int* __restrict__ ind, const unsigned short* __restrict__ ipwB,
    const float* __restrict__ ipb, unsigned short* __restrict__ qb,
    unsigned short* __restrict__ kb, unsigned short* __restrict__ vb) {
  __shared__ __align__(16) char ldsraw[52224];
  short* As = (short*)ldsraw;             // [64][136]
  short* Ws = (short*)(ldsraw + 17408);   // [128][136]
  const int t = threadIdx.x;
  const int lane = t & 63, wv = t >> 6;
  const int l15 = lane & 15, quad = lane >> 4;
  const int rbase = 32 * (wv >> 1), cbase = 64 * (wv & 1);
  const int mbase = blockIdx.x * 64;
  const int sec = blockIdx.y;
  f32x4 acc[2][4];
#pragma unroll
  for (int m = 0; m < 2; ++m)
#pragma unroll
    for (int n = 0; n < 4; ++n) acc[m][n] = (f32x4){0.f, 0.f, 0.f, 0.f};

  for (int fi = t; fi < 1024; fi += 256) {
    int row = fi >> 4, c8 = fi & 15;
    int vox = mbase + row;
    uint4 xv = ((const uint4*)x)[(size_t)vox * 16 + c8];
    if (sec < 2) {
      int s = ind[vox];
      const float4* pp = (const float4*)(pos + (size_t)s * 128 + c8 * 8);
      float4 p0 = pp[0], p1 = pp[1];
      float f0, f1, f2, f3, f4, f5, f6, f7;
      unpack2(xv.x, f0, f1); unpack2(xv.y, f2, f3);
      unpack2(xv.z, f4, f5); unpack2(xv.w, f6, f7);
      xv.x = pack2(f0 + p0.x, f1 + p0.y); xv.y = pack2(f2 + p0.z, f3 + p0.w);
      xv.z = pack2(f4 + p1.x, f5 + p1.y); xv.w = pack2(f6 + p1.z, f7 + p1.w);
    }
    *(uint4*)&As[row * 136 + c8 * 8] = xv;
  }
  for (int fi = t; fi < 2048; fi += 256) {
    int row = fi >> 4, c8 = fi & 15;
    ((uint4*)&Ws[row * 136])[c8] =
        ((const uint4*)(ipwB + (size_t)(sec * 128 + row) * 128))[c8];
  }
  __syncthreads();
  mma128(As, Ws, (rbase + l15) * 136 + quad * 8, (cbase + l15) * 136 + quad * 8, acc);
  __syncthreads();

  short* Ybf = (short*)ldsraw;  // [64][136]
#pragma unroll
  for (int nt = 0; nt < 4; ++nt) {
    int col = cbase + nt * 16 + l15;
    float bias = ipb[sec * 128 + col];
#pragma unroll
    for (int mt = 0; mt < 2; ++mt)
#pragma unroll
      for (int r = 0; r < 4; ++r)
        Ybf[(rbase + mt * 16 + quad * 4 + r) * 136 + col] =
            (short)f2bf(acc[mt][nt][r] + bias);
  }
  __syncthreads();
  unsigned short* dst = (sec == 0) ? qb : ((sec == 1) ? kb : vb);
  for (int fi = t; fi < 1024; fi += 256) {
    int row = fi >> 4, c8 = fi & 15;
    int s = ind[mbase + row];
    int slot = (s / 36) * 24 + (s % 36);
    ((uint4*)dst)[(size_t)slot * 16 + c8] = ((const uint4*)&Ybf[row * 136])[c8];
  }
}

// ---------------------------------------------------------------------------
__global__ __launch_bounds__(256) void attn_kernel(
    unsigned short* __restrict__ qb, const unsigned short* __restrict__ kb,
    const unsigned short* __restrict__ vb) {
  __shared__ float lds[14112];
  float* Qs = lds;          // [24][132]
  float* Ks = lds + 3168;
  float* Vs = lds + 6336;
  float* S = lds + 9504;    // [8][24][24]
  const int t = threadIdx.x;
  const size_t base = (size_t)blockIdx.x * 3072;
  for (int fi = t; fi < 1152; fi += 256) {
    int arr = fi / 384, rem = fi % 384;
    int row = rem >> 4, c8 = rem & 15;
    const unsigned short* src = arr == 0 ? qb : (arr == 1 ? kb : vb);
    uint4 raw = ((const uint4*)(src + base))[row * 16 + c8];
    float* dl = lds + arr * 3168 + row * 132 + c8 * 8;
    unpack2(raw.x, dl[0], dl[1]); unpack2(raw.y, dl[2], dl[3]);
    unpack2(raw.z, dl[4], dl[5]); unpack2(raw.w, dl[6], dl[7]);
  }
  __syncthreads();
  for (int idx = t; idx < 4608; idx += 256) {
    int hh = idx / 576, rem = idx % 576;
    int qq = rem / 24, kk = rem % 24;
    const float* qp = &Qs[qq * 132 + hh * 16];
    const float* kp = &Ks[kk * 132 + hh * 16];
    float s = 0.f;
#pragma unroll
    for (int d = 0; d < 16; ++d) s = fmaf(qp[d], kp[d], s);
    S[idx] = s * 0.25f;
  }
  __syncthreads();
  if (t < 192) {
    float* rowp = &S[t * 24];
    float m = rowp[0];
#pragma unroll
    for (int k2 = 1; k2 < 24; ++k2) m = fmaxf(m, rowp[k2]);
    float sum = 0.f;
#pragma unroll
    for (int k2 = 0; k2 < 24; ++k2) { float e = __expf(rowp[k2] - m); rowp[k2] = e; sum += e; }
    float inv = 1.f / sum;
#pragma unroll
    for (int k2 = 0; k2 < 24; ++k2) rowp[k2] *= inv;
  }
  __syncthreads();
  for (int idx = t; idx < 3072; idx += 256) {
    int hh = idx / 384, rem = idx % 384;
    int qq = rem >> 4, dd = rem & 15;
    const float* pp = &S[hh * 576 + qq * 24];
    const float* vp = &Vs[hh * 16 + dd];
    float o = 0.f;
#pragma unroll
    for (int k2 = 0; k2 < 24; ++k2) o = fmaf(pp[k2], vp[k2 * 132], o);
    qb[base + qq * 128 + hh * 16 + dd] = f2bf(o);
  }
}

// ---------------------------------------------------------------------------
__global__ __launch_bounds__(256) void outln_kernel(
    const unsigned short* __restrict__ o, const int* __restrict__ ind,
    const unsigned short* __restrict__ opwB, const float* __restrict__ opb,
    const unsigned short* __restrict__ xres, const float* __restrict__ lnw,
    const float* __restrict__ lnb, unsigned short* __restrict__ hout) {
  __shared__ __align__(16) char ldsraw[52224];
  short* As = (short*)ldsraw;
  short* Ws = (short*)(ldsraw + 17408);
  const int t = threadIdx.x;
  const int lane = t & 63, wv = t >> 6;
  const int l15 = lane & 15, quad = lane >> 4;
  const int rbase = 32 * (wv >> 1), cbase = 64 * (wv & 1);
  const int mbase = blockIdx.x * 64;
  f32x4 acc[2][4];
#pragma unroll
  for (int m = 0; m < 2; ++m)
#pragma unroll
    for (int n = 0; n < 4; ++n) acc[m][n] = (f32x4){0.f, 0.f, 0.f, 0.f};

  for (int fi = t; fi < 1024; fi += 256) {
    int row = fi >> 4, c8 = fi & 15;
    int s = ind[mbase + row];
    int slot = (s / 36) * 24 + (s % 36);
    *(uint4*)&As[row * 136 + c8 * 8] = ((const uint4*)o)[(size_t)slot * 16 + c8];
  }
  for (int fi = t; fi < 2048; fi += 256) {
    int row = fi >> 4, c8 = fi & 15;
    ((uint4*)&Ws[row * 136])[c8] = ((const uint4*)(opwB + (size_t)row * 128))[c8];
  }
  __syncthreads();
  mma128(As, Ws, (rbase + l15) * 136 + quad * 8, (cbase + l15) * 136 + quad * 8, acc);
  __syncthreads();

  float* Yf = (float*)ldsraw;               // [64][132]
  float* p1 = (float*)(ldsraw + 33792);
  float* p2 = (float*)(ldsraw + 34816);
  float* Ms = (float*)(ldsraw + 35840);
  float* Rs = (float*)(ldsraw + 36096);
#pragma unroll
  for (int nt = 0; nt < 4; ++nt) {
    int col = cbase + nt * 16 + l15;
    float bias = opb[col];
#pragma unroll
    for (int mt = 0; mt < 2; ++mt)
#pragma unroll
      for (int r = 0; r < 4; ++r)
        Yf[(rbase + mt * 16 + quad * 4 + r) * 132 + col] = acc[mt][nt][r] + bias;
  }
  __syncthreads();
  for (int fi = t; fi < 1024; fi += 256) {
    int row = fi >> 4, c8 = fi & 15;
    uint4 xv = ((const uint4*)xres)[(size_t)(mbase + row) * 16 + c8];
    float* yp = &Yf[row * 132 + c8 * 8];
    float a, b;
    unpack2(xv.x, a, b); yp[0] += a; yp[1] += b;
    unpack2(xv.y, a, b); yp[2] += a; yp[3] += b;
    unpack2(xv.z, a, b); yp[4] += a; yp[5] += b;
    unpack2(xv.w, a, b); yp[6] += a; yp[7] += b;
  }
  __syncthreads();
  {
    int r = t & 63, g = t >> 6;
    float s = 0.f, s2 = 0.f;
    for (int c = g * 32; c < g * 32 + 32; ++c) { float v = Yf[r * 132 + c]; s += v; s2 += v * v; }
    p1[g * 64 + r] = s; p2[g * 64 + r] = s2;
  }
  __syncthreads();
  if (t < 64) {
    float s = p1[t] + p1[64 + t] + p1[128 + t] + p1[192 + t];
    float s2 = p2[t] + p2[64 + t] + p2[128 + t] + p2[192 + t];
    float m = s * (1.f / 128.f);
    float var = s2 * (1.f / 128.f) - m * m;
    Ms[t] = m; Rs[t] = rsqrtf(var + 1e-5f);
  }
  __syncthreads();
  for (int fi = t; fi < 1024; fi += 256) {
    int row = fi >> 4, c8 = fi & 15;
    float m = Ms[row], rr = Rs[row];
    const float* yp = &Yf[row * 132 + c8 * 8];
    uint4 ov;
    float v0, v1;
#define LNPAIR(J, FLD) \
    v0 = (yp[2*J] - m) * rr * lnw[c8*8+2*J] + lnb[c8*8+2*J]; \
    v1 = (yp[2*J+1] - m) * rr * lnw[c8*8+2*J+1] + lnb[c8*8+2*J+1]; \
    ov.FLD = pack2(v0, v1);
    LNPAIR(0, x) LNPAIR(1, y) LNPAIR(2, z) LNPAIR(3, w)
#undef LNPAIR
    ((uint4*)hout)[(size_t)(mbase + row) * 16 + c8] = ov;
  }
}

// ---------------------------------------------------------------------------
__global__ __launch_bounds__(256) void ffn1_kernel(
    const unsigned short* __restrict__ h, const unsigned short* __restrict__ w1B,
    const float* __restrict__ b1, unsigned short* __restrict__ ff) {
  __shared__ __align__(16) char ldsraw[52224];
  short* As = (short*)ldsraw;
  short* Ws = (short*)(ldsraw + 17408);
  const int t = threadIdx.x;
  const int lane = t & 63, wv = t >> 6;
  const int l15 = lane & 15, quad = lane >> 4;
  const int rbase = 32 * (wv >> 1), cbase = 64 * (wv & 1);
  const int mbase = blockIdx.x * 64;
  const int by = blockIdx.y;
  f32x4 acc[2][4];
#pragma unroll
  for (int m = 0; m < 2; ++m)
#pragma unroll
    for (int n = 0; n < 4; ++n) acc[m][n] = (f32x4){0.f, 0.f, 0.f, 0.f};

  for (int fi = t; fi < 1024; fi += 256) {
    int row = fi >> 4, c8 = fi & 15;
    *(uint4*)&As[row * 136 + c8 * 8] = ((const uint4*)h)[(size_t)(mbase + row) * 16 + c8];
  }
  for (int fi = t; fi < 2048; fi += 256) {
    int row = fi >> 4, c8 = fi & 15;
    ((uint4*)&Ws[row * 136])[c8] =
        ((const uint4*)(w1B + (size_t)(by * 128 + row) * 128))[c8];
  }
  __syncthreads();
  mma128(As, Ws, (rbase + l15) * 136 + quad * 8, (cbase + l15) * 136 + quad * 8, acc);
  __syncthreads();

  short* Ybf = (short*)ldsraw;
#pragma unroll
  for (int nt = 0; nt < 4; ++nt) {
    int col = cbase + nt * 16 + l15;
    float bias = b1[by * 128 + col];
#pragma unroll
    for (int mt = 0; mt < 2; ++mt)
#pragma unroll
      for (int r = 0; r < 4; ++r) {
        float v = acc[mt][nt][r] + bias;
        float g = 0.5f * v * (1.f + erff(v * 0.70710678f));
        Ybf[(rbase + mt * 16 + quad * 4 + r) * 136 + col] = (short)f2bf(g);
      }
  }
  __syncthreads();
  for (int fi = t; fi < 1024; fi += 256) {
    int row = fi >> 4, c8 = fi & 15;
    ((uint4*)ff)[(size_t)(mbase + row) * 32 + by * 16 + c8] =
        ((const uint4*)&Ybf[row * 136])[c8];
  }
}

// ---------------------------------------------------------------------------
__global__ __launch_bounds__(256) void ffn2_kernel(
    const unsigned short* __restrict__ ff, const unsigned short* __restrict__ w2B,
    const float* __restrict__ b2, const unsigned short* __restrict__ hres,
    const float* __restrict__ lnw, const float* __restrict__ lnb,
    unsigned short* __restrict__ xout) {
  __shared__ __align__(16) char ldsraw[52224];
  short* As = (short*)ldsraw;
  short* Ws = (short*)(ldsraw + 17408);
  const int t = threadIdx.x;
  const int lane = t & 63, wv = t >> 6;
  const int l15 = lane & 15, quad = lane >> 4;
  const int rbase = 32 * (wv >> 1), cbase = 64 * (wv & 1);
  const int mbase = blockIdx.x * 64;
  f32x4 acc[2][4];
#pragma unroll
  for (int m = 0; m < 2; ++m)
#pragma unroll
    for (int n = 0; n < 4; ++n) acc[m][n] = (f32x4){0.f, 0.f, 0.f, 0.f};

  for (int k2 = 0; k2 < 2; ++k2) {
    if (k2) __syncthreads();
    for (int fi = t; fi < 1024; fi += 256) {
      int row = fi >> 4, c8 = fi & 15;
      *(uint4*)&As[row * 136 + c8 * 8] =
          ((const uint4*)ff)[(size_t)(mbase + row) * 32 + k2 * 16 + c8];
    }
    for (int fi = t; fi < 2048; fi += 256) {
      int row = fi >> 4, c8 = fi & 15;
      ((uint4*)&Ws[row * 136])[c8] =
          ((const uint4*)(w2B + (size_t)row * 256 + k2 * 128))[c8];
    }
    __syncthreads();
    mma128(As, Ws, (rbase + l15) * 136 + quad * 8, (cbase + l15) * 136 + quad * 8, acc);
  }
  __syncthreads();

  float* Yf = (float*)ldsraw;
  float* p1 = (float*)(ldsraw + 33792);
  float* p2 = (float*)(ldsraw + 34816);
  float* Ms = (float*)(ldsraw + 35840);
  float* Rs = (float*)(ldsraw + 36096);
#pragma unroll
  for (int nt = 0; nt < 4; ++nt) {
    int col = cbase + nt * 16 + l15;
    float bias = b2[col];
#pragma unroll
    for (int mt = 0; mt < 2; ++mt)
#pragma unroll
      for (int r = 0; r < 4; ++r)
        Yf[(rbase + mt * 16 + quad * 4 + r) * 132 + col] = acc[mt][nt][r] + bias;
  }
  __syncthreads();
  for (int fi = t; fi < 1024; fi += 256) {
    int row = fi >> 4, c8 = fi & 15;
    uint4 xv = ((const uint4*)hres)[(size_t)(mbase + row) * 16 + c8];
    float* yp = &Yf[row * 132 + c8 * 8];
    float a, b;
    unpack2(xv.x, a, b); yp[0] += a; yp[1] += b;
    unpack2(xv.y, a, b); yp[2] += a; yp[3] += b;
    unpack2(xv.z, a, b); yp[4] += a; yp[5] += b;
    unpack2(xv.w, a, b); yp[6] += a; yp[7] += b;
  }
  __syncthreads();
  {
    int r = t & 63, g = t >> 6;
    float s = 0.f, s2 = 0.f;
    for (int c = g * 32; c < g * 32 + 32; ++c) { float v = Yf[r * 132 + c]; s += v; s2 += v * v; }
    p1[g * 64 + r] = s; p2[g * 64 + r] = s2;
  }
  __syncthreads();
  if (t < 64) {
    float s = p1[t] + p1[64 + t] + p1[128 + t] + p1[192 + t];
    float s2 = p2[t] + p2[64 + t] + p2[128 + t] + p2[192 + t];
    float m = s * (1.f / 128.f);
    float var = s2 * (1.f / 128.f) - m * m;
    Ms[t] = m; Rs[t] = rsqrtf(var + 1e-5f);
  }
  __syncthreads();
  for (int fi = t; fi < 1024; fi += 256) {
    int row = fi >> 4, c8 = fi & 15;
    float m = Ms[row], rr = Rs[row];
    const float* yp = &Yf[row * 132 + c8 * 8];
    uint4 ov;
    float v0, v1;
#define LNPAIR(J, FLD) \
    v0 = (yp[2*J] - m) * rr * lnw[c8*8+2*J] + lnb[c8*8+2*J]; \
    v1 = (yp[2*J+1] - m) * rr * lnw[c8*8+2*J+1] + lnb[c8*8+2*J+1]; \
    ov.FLD = pack2(v0, v1);
    LNPAIR(0, x) LNPAIR(1, y) LNPAIR(2, z) LNPAIR(3, w)
#undef LNPAIR
    ((uint4*)xout)[(size_t)(mbase + row) * 16 + c8] = ov;
  }
}

// ---------------------------------------------------------------------------
__global__ void idx_init_kernel(int* __restrict__ idxmap) {
  int i = blockIdx.x * 256 + threadIdx.x;
  if (i < 2 * HWPIX) idxmap[i] = -1;
}

__global__ void scatter_kernel(const int* __restrict__ coors, int* __restrict__ idxmap) {
  int i = blockIdx.x * 256 + threadIdx.x;
  if (i >= NVOX) return;
  int b = coors[i * 4 + 0], y = coors[i * 4 + 2], xx = coors[i * 4 + 3];
  atomicMax(&idxmap[b * HWPIX + y * 320 + xx], i);
}

__global__ void canvas_kernel(const unsigned short* __restrict__ x,
                              const int* __restrict__ idxmap,
                              unsigned short* __restrict__ canvas) {
  int idx = blockIdx.x * 256 + threadIdx.x;
  if (idx >= 2 * HWPIX * 16) return;
  int cell = idx >> 4, c8 = idx & 15;
  int vox = idxmap[cell];
  uint4 v = {0u, 0u, 0u, 0u};
  if (vox >= 0) v = ((const uint4*)x)[(size_t)vox * 16 + c8];
  ((uint4*)canvas)[idx] = v;
}

// ---------------------------------------------------------------------------
// Conv 3x3 pad 1, NHWC bf16 in. Block: 64 px (row segment) x 128 cout.
template <int NCHW_OUT>
__global__ __launch_bounds__(256) void conv_kernel(
    const unsigned short* __restrict__ in, const unsigned short* __restrict__ wTb,
    void* __restrict__ outp) {
  __shared__ __align__(16) char ldsraw[52768];
  short* patch = (short*)ldsraw;           // [66 cols][136 ci]
  short* Wt = (short*)(ldsraw + 17952);    // [128 co][136 ci]
  const int t = threadIdx.x;
  const int lane = t & 63, wv = t >> 6;
  const int l15 = lane & 15, quad = lane >> 4;
  const int rbase = 32 * (wv >> 1), cbase = 64 * (wv & 1);
  const int x0 = blockIdx.x * 64;
  const int y = blockIdx.y;
  const int b = blockIdx.z;
  const unsigned short* inb = in + (size_t)b * HWPIX * 128;
  f32x4 acc[2][4];
#pragma unroll
  for (int m = 0; m < 2; ++m)
#pragma unroll
    for (int n = 0; n < 4; ++n) acc[m][n] = (f32x4){0.f, 0.f, 0.f, 0.f};

  for (int dy = 0; dy < 3; ++dy) {
    __syncthreads();
    int gy = y + dy - 1;
    for (int fi = t; fi < 1056; fi += 256) {
      int col = fi >> 4, c8 = fi & 15;
      int gx = x0 + col - 1;
      uint4 v = {0u, 0u, 0u, 0u};
      if (gy >= 0 && gy < 320 && gx >= 0 && gx < 320)
        v = ((const uint4*)inb)[(size_t)(gy * 320 + gx) * 16 + c8];
      *(uint4*)&patch[col * 136 + c8 * 8] = v;
    }
    for (int dx = 0; dx < 3; ++dx) {
      __syncthreads();
      int tap = dy * 3 + dx;
      for (int fi = t; fi < 2048; fi += 256) {
        int row = fi >> 4, c8 = fi & 15;
        ((uint4*)&Wt[row * 136])[c8] =
            ((const uint4*)(wTb + (size_t)(tap * 128 + row) * 128))[c8];
      }
      __syncthreads();
      mma128(patch, Wt, (rbase + l15 + dx) * 136 + quad * 8,
             (cbase + l15) * 136 + quad * 8, acc);
    }
  }
  __syncthreads();
  if (NCHW_OUT) {
    float* Yf = (float*)ldsraw;  // [128 co][68 px]
#pragma unroll
    for (int nt = 0; nt < 4; ++nt) {
      int col = cbase + nt * 16 + l15;
#pragma unroll
      for (int mt = 0; mt < 2; ++mt)
#pragma unroll
        for (int r = 0; r < 4; ++r)
          Yf[col * 68 + rbase + mt * 16 + quad * 4 + r] = fmaxf(acc[mt][nt][r], 0.f);
    }
    __syncthreads();
    float* out = (float*)outp;
    for (int fi = t; fi < 2048; fi += 256) {
      int co = fi >> 4, q4 = fi & 15;
      float4 v = *(float4*)&Yf[co * 68 + q4 * 4];
      *(float4*)&out[(size_t)(b * 128 + co) * HWPIX + y * 320 + x0 + q4 * 4] = v;
    }
  } else {
    short* Ybf = (short*)ldsraw;  // [64 px][136 co]
#pragma unroll
    for (int nt = 0; nt < 4; ++nt) {
      int col = cbase + nt * 16 + l15;
#pragma unroll
      for (int mt = 0; mt < 2; ++mt)
#pragma unroll
        for (int r = 0; r < 4; ++r)
          Ybf[(rbase + mt * 16 + quad * 4 + r) * 136 + col] =
              (short)f2bf(fmaxf(acc[mt][nt][r], 0.f));
    }
    __syncthreads();
    unsigned short* out = (unsigned short*)outp;
    for (int fi = t; fi < 1024; fi += 256) {
      int row = fi >> 4, c8 = fi & 15;
      ((uint4*)out)[((size_t)b * HWPIX + y * 320 + x0 + row) * 16 + c8] =
          ((const uint4*)&Ybf[row * 136])[c8];
    }
  }
}

// ============================================================================
extern "C" void kernel_launch(void* const* d_in, const int* in_sizes, int n_in,
                              void* d_out, int out_size, void* d_ws, size_t ws_size,
                              hipStream_t stream) {
  const float* voxel_feats = (const float*)d_in[0];
  const float* pos0 = (const float*)d_in[1];
  const float* pos1 = (const float*)d_in[2];
  const float* ipw = (const float*)d_in[3];
  const float* ipb = (const float*)d_in[4];
  const float* opw = (const float*)d_in[5];
  const float* opb = (const float*)d_in[6];
  const float* l1w = (const float*)d_in[7];
  const float* l1b = (const float*)d_in[8];
  const float* l2w = (const float*)d_in[9];
  const float* l2b = (const float*)d_in[10];
  const float* n1w = (const float*)d_in[11];
  const float* n1b = (const float*)d_in[12];
  const float* n2w = (const float*)d_in[13];
  const float* n2b = (const float*)d_in[14];
  const float* convw = (const float*)d_in[15];
  const int* coors = (const int*)d_in[16];
  const int* ind0 = (const int*)d_in[17];
  const int* ind1 = (const int*)d_in[18];

  unsigned short* ws = (unsigned short*)d_ws;
  const size_t NC = (size_t)NVOX * CDIM;  // 15,360,000
  unsigned short* bx = ws;
  unsigned short* bq = ws + NC;
  unsigned short* bk = ws + 2 * NC;
  unsigned short* bv = ws + 3 * NC;
  unsigned short* bh = ws + 4 * NC;
  unsigned short* bff = ws + 5 * NC;       // 2*NC
  unsigned short* wB = ws + 7 * NC;        // 819200 bf16 weights
  unsigned short* ipwB = wB;               // 196608
  unsigned short* opwB = wB + 196608;      // 65536
  unsigned short* l1wB = wB + 262144;      // 131072
  unsigned short* l2wB = wB + 393216;      // 131072
  unsigned short* convB = wB + 524288;     // 294912
  int* idxmap = (int*)(wB + 819200);       // 204800 ints
  unsigned short* canvas = bq;             // 26.2M <= 2*NC (bq..bk)
  unsigned short* c1out = bv;              // 26.2M <= 2*NC (bv..bh)

  cvt_kernel<<<15000, 256, 0, stream>>>(voxel_feats, bx, 3840000);
  cvt_kernel<<<192, 256, 0, stream>>>(ipw, ipwB, 49152);
  cvt_kernel<<<64, 256, 0, stream>>>(opw, opwB, 16384);
  cvt_kernel<<<128, 256, 0, stream>>>(l1w, l1wB, 32768);
  cvt_kernel<<<128, 256, 0, stream>>>(l2w, l2wB, 32768);
  cvtT_kernel<<<1152, 256, 0, stream>>>(convw, convB);

  for (int l = 0; l < 4; ++l) {
    const int* ind = (l & 1) ? ind1 : ind0;
    const float* pos = (l & 1) ? pos1 : pos0;
    qkv_kernel<<<dim3(1875, 3), 256, 0, stream>>>(
        bx, pos, ind, ipwB + (size_t)l * 49152, ipb + l * 384, bq, bk, bv);
    attn_kernel<<<NWIN, 256, 0, stream>>>(bq, bk, bv);
    outln_kernel<<<1875, 256, 0, stream>>>(
        bq, ind, opwB + (size_t)l * 16384, opb + l * 128, bx,
        n1w + l * 128, n1b + l * 128, bh);
    ffn1_kernel<<<dim3(1875, 2), 256, 0, stream>>>(
        bh, l1wB + (size_t)l * 32768, l1b + l * 256, bff);
    ffn2_kernel<<<1875, 256, 0, stream>>>(
        bff, l2wB + (size_t)l * 32768, l2b + l * 128, bh,
        n2w + l * 128, n2b + l * 128, bx);
  }

  idx_init_kernel<<<800, 256, 0, stream>>>(idxmap);
  scatter_kernel<<<(NVOX + 255) / 256, 256, 0, stream>>>(coors, idxmap);
  canvas_kernel<<<12800, 256, 0, stream>>>(bx, idxmap, canvas);

  conv_kernel<0><<<dim3(5, 320, 2), 256, 0, stream>>>(canvas, convB, (void*)c1out);
  conv_kernel<1><<<dim3(5, 320, 2), 256, 0, stream>>>(c1out, convB + 9 * 16384, d_out);
}